// Round 1
// 191.953 us; speedup vs baseline: 1.1072x; 1.1072x over previous
//
#include <hip/hip_runtime.h>
#include <stdint.h>

// VQ-VAE forward on MI355X — round 5.
// d_out (fp32): out[4194304] | loss[1] | perplexity[1] | idx_as_float[16384]
//
// prep_w   : weight -> fp16 fragment-major chunks (16 codes): per chunk 8 ks-blocks
//            of 1024B in exact MFMA-fragment lane order + 64B hw bias row at +8192
//            (chunk stride 9216B). hw = 1024 - |w|^2/2 folded into MFMA C-init.
// gemm     : 512 blocks x 4 waves (M_BLOCK=256 rows), SHARED double-buffered LDS
//            chunk staged cooperatively (2x16B global_load_lds + 1x4B hw per wave).
//            Counted s_waitcnt vmcnt(3) (never 0 in loop) + raw s_barrier pairs;
//            contiguous ds_read_b128 (no swizzle, no bank conflicts); s_setprio
//            around MFMA cluster. 8 splits XCD-pinned; packed-key top-2 per split.
// finish   : prune candidates by approx score (margin 0.5), fp64 rescore survivors ->
//            exact idx, counts, loss; gather weight[idx] -> out (LDS transposed).
// finalize : perplexity + loss scale.

#define M_TOTAL 16384
#define N_CODES 8192
#define KDIM    256
#define SPATIAL 4096
#define NSPLIT  8
#define CODES_PER_SPLIT  1024
#define CHUNK_CODES      16
#define CHUNKS_PER_SPLIT 64
#define CHUNK_BYTES      9216       // 8192 data + 64 hw + 960 pad
#define CHUNK_HALFS      4608
#define M_BLOCK          256

typedef _Float16 v8hf __attribute__((ext_vector_type(8)));
typedef _Float16 v4hf __attribute__((ext_vector_type(4)));
typedef float    v4f  __attribute__((ext_vector_type(4)));

// s_waitcnt imm (gfx9 encoding): [3:0] vmcnt lo, [6:4] expcnt, [11:8] lgkmcnt, [15:14] vmcnt hi
#define WAITCNT_VM3   0x0F73   // vmcnt(3),  lgkm/exp no-wait
#define WAITCNT_VM0   0x0F70   // vmcnt(0),  lgkm/exp no-wait
#define WAITCNT_LGKM0 0xC07F   // lgkmcnt(0), vm/exp no-wait

// ---------------------------------------------------------------- prep_w (+init)
// 2048 blocks x 256 thr; one wave per code row.
// Fragment-major layout: code n -> chunk g = n>>4, row = n&15. Element k lives in
// granule gr = k>>3 (16B); gemm lane L = q*16+r reads granule (ks*4+q) of code r at
// chunk byte ks*1024 + L*16. prep lane covers k = lane*4..+4 -> gr = lane>>1,
// half hh = lane&1. hw bias floats at chunk byte 8192 + row*4.
__global__ __launch_bounds__(256) void prep_w_kernel(
    const float* __restrict__ w, _Float16* __restrict__ wpk,
    int* __restrict__ counts, double* __restrict__ loss_acc)
{
    const int t = threadIdx.x;
    const int n = blockIdx.x * 4 + (t >> 6);
    const int lane = t & 63;
    v4f v = ((const v4f*)(w + (size_t)n * KDIM))[lane];
    v4hf hv;
    float s = 0.0f;
#pragma unroll
    for (int j = 0; j < 4; j++) {
        float f = v[j];
        s += f * f;
        hv[j] = (_Float16)f;
    }
    const int chunk = n >> 4;
    const int row   = n & 15;
    const int ks = lane >> 3;            // granule>>2
    const int qq = (lane >> 1) & 3;      // granule&3
    const int hh = lane & 1;
    size_t off = (size_t)chunk * CHUNK_HALFS + ks * 512 + qq * 128 + row * 8 + hh * 4;
    *(v4hf*)(wpk + off) = hv;
#pragma unroll
    for (int o = 32; o >= 1; o >>= 1) s += __shfl_xor(s, o);
    if (lane == 0) {
        float* hwp = (float*)((char*)wpk + (size_t)chunk * CHUNK_BYTES + 8192);
        hwp[row] = 1024.0f - 0.5f * s;   // C-init bias: acc = hw + dot > 0
    }
    const int gi = blockIdx.x * 256 + t;
    if (gi < N_CODES) counts[gi] = 0;
    if (gi == 0) *loss_acc = 0.0;
}

// ---------------------------------------------------------------- top-2 MAX merge (key desc, n asc on tie)
__device__ __forceinline__ void top2max_merge(uint32_t& v1, int& i1, uint32_t& v2, int& i2,
                                              uint32_t o1, int oi1, uint32_t o2, int oi2) {
    bool ob = (o1 > v1) || (o1 == v1 && oi1 < i1);
    uint32_t n1v, n2v; int n1i, n2i;
    if (ob) {
        bool t2 = (v1 > o2) || (v1 == o2 && i1 < oi2);
        n1v = o1; n1i = oi1;
        n2v = t2 ? v1 : o2; n2i = t2 ? i1 : oi2;
    } else {
        bool t2 = (o1 > v2) || (o1 == v2 && oi1 < i2);
        n1v = v1; n1i = i1;
        n2v = t2 ? o1 : v2; n2i = t2 ? oi1 : i2;
    }
    v1 = n1v; i1 = n1i; v2 = n2v; i2 = n2i;
}

// ---------------------------------------------------------------- gemm
// grid 512 = 64 row-blocks x 8 splits (split = bid&7 -> XCD-pinned); block = 4 waves.
// Shared dbuf LDS, counted vmcnt(3), 2 raw barriers per chunk.
__global__ __launch_bounds__(256, 2) void gemm_kernel(
    const float* __restrict__ z,
    const _Float16* __restrict__ wpk,
    int4* __restrict__ candbuf)          // [M_TOTAL][8] = {k1,n1,k2,n2}
{
    __shared__ __align__(16) _Float16 lds[2][CHUNK_HALFS];   // 2 x 9216 B

    const int bid   = blockIdx.x;
    const int split = bid & 7;
    const int rb    = bid >> 3;            // 0..63
    const int i0    = rb * M_BLOCK;
    const int b     = i0 >> 12;
    const int s0    = i0 & (SPATIAL - 1);
    const int tid   = threadIdx.x;
    const int wid   = tid >> 6;
    const int lane  = tid & 63;
    const int r     = lane & 15;
    const int q     = lane >> 4;

    const char* wsplit = (const char*)wpk + (size_t)split * CHUNKS_PER_SPLIT * CHUNK_BYTES;

    // cooperative stage: wave wid loads ks-blocks {2*wid, 2*wid+1} (16B/lane) + its
    // 256B slice of the hw/pad row (4B/lane) => exactly 3 vmem per wave per chunk.
    auto stage = [&](int c, int buf) {
        const char* gb = wsplit + (size_t)c * CHUNK_BYTES;
        char* lb = (char*)&lds[buf][0];
#pragma unroll
        for (int j = 0; j < 2; j++) {
            const int o = (wid * 2 + j) * 1024 + lane * 16;
            __builtin_amdgcn_global_load_lds(
                (const __attribute__((address_space(1))) void*)(gb + o),
                (__attribute__((address_space(3))) void*)(lb + o), 16, 0, 0);
        }
        const int oh = 8192 + wid * 256 + lane * 4;
        __builtin_amdgcn_global_load_lds(
            (const __attribute__((address_space(1))) void*)(gb + oh),
            (__attribute__((address_space(3))) void*)(lb + oh), 4, 0, 0);
    };

    stage(0, 0);
    stage(1, 1);

    // ---- A fragments: 4 m-tiles x 8 ks (rows i0 + wid*64 .. +63); overlap stage latency
    v8hf a[4][8];
    {
        const float* zb = z + ((size_t)b << 20) + (size_t)(s0 + wid * 64 + r);
#pragma unroll
        for (int mt = 0; mt < 4; mt++) {
#pragma unroll
            for (int ks = 0; ks < 8; ks++) {
                const int kbase = ks * 32 + q * 8;
#pragma unroll
                for (int j = 0; j < 8; j++)
                    a[mt][ks][j] = (_Float16)zb[((size_t)(kbase + j) << 12) + mt * 16];
            }
        }
    }

    uint32_t k1[4][4], k2[4][4];
#pragma unroll
    for (int mt = 0; mt < 4; mt++)
#pragma unroll
    for (int g = 0; g < 4; g++) { k1[mt][g] = 0u; k2[mt][g] = 0u; }

    auto compute = [&](int it, int buf) {
        const char* lb = (const char*)&lds[buf][0];
        const float hwv = *(const float*)(lb + 8192 + r * 4);
        v4f acc[4];
#pragma unroll
        for (int mt = 0; mt < 4; mt++) acc[mt] = (v4f){hwv, hwv, hwv, hwv};

        __builtin_amdgcn_s_setprio(1);
#pragma unroll
        for (int ks = 0; ks < 8; ks++) {
            v8hf bh = *(const v8hf*)(lb + ks * 1024 + lane * 16);   // contiguous: no conflicts
#pragma unroll
            for (int mt = 0; mt < 4; mt++)
                acc[mt] = __builtin_amdgcn_mfma_f32_16x16x32_f16(a[mt][ks], bh, acc[mt], 0, 0, 0);
        }
        __builtin_amdgcn_s_setprio(0);

        // top-2 MAX of packed key: acc bits (distance = 2048 - 2*acc) | 6-bit chunk tag
        const uint32_t tag = (uint32_t)it;
#pragma unroll
        for (int mt = 0; mt < 4; mt++)
#pragma unroll
        for (int g = 0; g < 4; g++) {
            uint32_t key = (__float_as_uint(acc[mt][g]) & 0xFFFFFFC0u) | tag;
            uint32_t o1 = k1[mt][g], o2 = k2[mt][g];
            uint32_t mn = key < o1 ? key : o1;
            k2[mt][g] = o2 > mn ? o2 : mn;
            k1[mt][g] = key > o1 ? key : o1;
        }
    };

    // prologue drain: A-loads + stages 0,1 complete; enter loop with 0 outstanding.
    __builtin_amdgcn_s_waitcnt(WAITCNT_VM0);
    __builtin_amdgcn_s_barrier();

    // steady state: at body(c) top, outstanding = trio(c)+trio(c+1) <= 6; vmcnt(3)
    // retires trio(c). Loop never drains vmcnt to 0.
#pragma unroll 2
    for (int it = 0; it < CHUNKS_PER_SPLIT - 2; it++) {
        const int buf = it & 1;
        __builtin_amdgcn_s_waitcnt(WAITCNT_VM3);    // my trio(it) landed
        __builtin_amdgcn_s_barrier();               // everyone's trio(it) landed
        compute(it, buf);
        __builtin_amdgcn_s_waitcnt(WAITCNT_LGKM0);  // my ds_reads of buf drained
        __builtin_amdgcn_s_barrier();               // everyone's reads drained
        stage(it + 2, buf);                         // overwrite buf with chunk it+2
    }
    // body 62: trio(62) retires under vmcnt(3) (trio(63) stays in flight)
    __builtin_amdgcn_s_waitcnt(WAITCNT_VM3);
    __builtin_amdgcn_s_barrier();
    compute(CHUNKS_PER_SPLIT - 2, 0);
    // body 63: final drain
    __builtin_amdgcn_s_waitcnt(WAITCNT_VM0);
    __builtin_amdgcn_s_barrier();
    compute(CHUNKS_PER_SPLIT - 1, 1);

    // decode n, cross-lane top-2 over the 16 r-lanes, write per-split candidates
    const int nsbase = split * CODES_PER_SPLIT + r;
#pragma unroll
    for (int mt = 0; mt < 4; mt++) {
#pragma unroll
        for (int g = 0; g < 4; g++) {
            uint32_t K1 = k1[mt][g], K2 = k2[mt][g];
            int n1 = nsbase + (int)((K1 & 63u) << 4);
            int n2 = nsbase + (int)((K2 & 63u) << 4);
#pragma unroll
            for (int off = 1; off < 16; off <<= 1) {
                uint32_t o1 = __shfl_xor(K1, off);
                int     on1 = __shfl_xor(n1, off);
                uint32_t o2 = __shfl_xor(K2, off);
                int     on2 = __shfl_xor(n2, off);
                top2max_merge(K1, n1, K2, n2, o1, on1, o2, on2);
            }
            if (r == 0) {
                const int row = i0 + wid * 64 + mt * 16 + q * 4 + g;
                candbuf[(size_t)row * 8 + split] = make_int4((int)K1, n1, (int)K2, n2);
            }
        }
    }
}

// ---------------------------------------------------------------- finish
// 512 blocks x 256 thr, 32 rows: prune by approx score, fp64 rescore survivors,
// exact idx + counts + loss; gather weight[idx] -> out.
__global__ __launch_bounds__(256) void finish_kernel(
    const float* __restrict__ z, const float* __restrict__ weight,
    const int4* __restrict__ candbuf,
    int* __restrict__ counts, double* __restrict__ loss_acc,
    float* __restrict__ out, float* __restrict__ out_idx_f)
{
    __shared__ int4  s_cand[32][8];
    __shared__ float s_zw[32][KDIM + 1];
    __shared__ int   s_fi[32];
    __shared__ double s_loss[4];

    const int i0 = blockIdx.x * 32;
    const int b  = i0 >> 12;
    const int s0 = i0 & (SPATIAL - 1);
    const int t  = threadIdx.x;

    s_cand[t >> 3][t & 7] = candbuf[(size_t)(i0 + (t >> 3)) * 8 + (t & 7)];

    // z tile transpose: coalesced global -> LDS
    for (int e = t; e < 32 * KDIM; e += 256) {
        const int c = e >> 5, rr = e & 31;
        s_zw[rr][c] = z[((size_t)b << 20) + ((size_t)c << 12) + s0 + rr];
    }
    __syncthreads();

    const int row = t >> 3, seg = t & 7;
    float zs[32];
#pragma unroll
    for (int j = 0; j < 32; j++) zs[j] = s_zw[row][seg * 32 + j];

    // approx distances + min
    float da[16];
    float dmin_a = 3.4e38f;
#pragma unroll
    for (int sp = 0; sp < 8; sp++) {
        int4 c = s_cand[row][sp];
        da[sp * 2]     = 2048.0f - 2.0f * __uint_as_float((uint32_t)c.x & 0xFFFFFFC0u);
        da[sp * 2 + 1] = 2048.0f - 2.0f * __uint_as_float((uint32_t)c.z & 0xFFFFFFC0u);
        dmin_a = fminf(dmin_a, fminf(da[sp * 2], da[sp * 2 + 1]));
    }
    const float cutoff = dmin_a + 0.5f;

    double dbest = 1e300; int nbest = 0x7fffffff;
#pragma unroll 1
    for (int c = 0; c < 16; c++) {
        if (da[c] > cutoff) continue;
        int4 cc = s_cand[row][c >> 1];
        const int n = (c & 1) ? cc.w : cc.y;
        const float* wr = weight + (size_t)n * KDIM + seg * 32;
        double d = 0.0;
#pragma unroll
        for (int j = 0; j < 32; j++) {
            double df = (double)zs[j] - (double)wr[j];
            d += df * df;
        }
#pragma unroll
        for (int o = 1; o < 8; o <<= 1) d += __shfl_xor(d, o);
        if (d < dbest || (d == dbest && n < nbest)) { dbest = d; nbest = n; }
    }

    double lsum = 0.0;
    if (seg == 0) {
        s_fi[row] = nbest;
        out_idx_f[i0 + row] = (float)nbest;
        atomicAdd(&counts[nbest], 1);
        lsum = dbest;
    }
#pragma unroll
    for (int o = 1; o < 64; o <<= 1) lsum += __shfl_xor(lsum, o);
    if ((t & 63) == 0) s_loss[t >> 6] = lsum;
    __syncthreads();
    if (t == 0) atomicAdd(loss_acc, s_loss[0] + s_loss[1] + s_loss[2] + s_loss[3]);

    // gather weight[fi] -> LDS (reuse s_zw) -> transposed coalesced write
    for (int e = t; e < 32 * KDIM; e += 256) {
        const int rr = e >> 8, c = e & 255;
        s_zw[rr][c] = weight[(size_t)s_fi[rr] * KDIM + c];
    }
    __syncthreads();
    const int m = t & 31, c0 = t >> 5;
    const size_t obase = ((size_t)b << 20) + (size_t)(s0 + m);
    for (int c = c0; c < KDIM; c += 8)
        out[obase + ((size_t)c << 12)] = s_zw[m][c];
}

// ---------------------------------------------------------------- finalize
__global__ void finalize_kernel(const int* __restrict__ counts,
                                const double* __restrict__ loss_acc,
                                float* __restrict__ out_scalars)
{
    const int t = threadIdx.x;
    double s = 0.0;
    for (int n = t; n < N_CODES; n += 256) {
        double p = (double)counts[n] / (double)M_TOTAL;
        s -= p * log(p + 1e-10);
    }
#pragma unroll
    for (int o = 32; o >= 1; o >>= 1) s += __shfl_xor(s, o);
    __shared__ double sds[4];
    if ((t & 63) == 0) sds[t >> 6] = s;
    __syncthreads();
    if (t == 0) {
        double tot = sds[0] + sds[1] + sds[2] + sds[3];
        out_scalars[0] = (float)(0.25 * (*loss_acc) / (double)(M_TOTAL * KDIM));
        out_scalars[1] = (float)exp(tot);
    }
}

// ---------------------------------------------------------------- launch
extern "C" void kernel_launch(void* const* d_in, const int* in_sizes, int n_in,
                              void* d_out, int out_size, void* d_ws, size_t ws_size,
                              hipStream_t stream) {
    const float* z      = (const float*)d_in[0];   // 4*256*16*16*16
    const float* weight = (const float*)d_in[1];   // 8192*256
    float* out = (float*)d_out;

    size_t off = 0;
    auto carve = [&](size_t bytes) {
        void* p = (char*)d_ws + off;
        off += (bytes + 255) & ~(size_t)255;
        return p;
    };
    _Float16* wpk     = (_Float16*)carve((size_t)(N_CODES / CHUNK_CODES) * CHUNK_BYTES); // 4.72 MB
    int4*     candbuf = (int4*)    carve((size_t)M_TOTAL * 8 * 16);                      // 2 MB
    int*      counts  = (int*)     carve((size_t)N_CODES * 4);
    double*   lossac  = (double*)  carve(16);

    float* out_scalars = out + (size_t)4 * KDIM * SPATIAL;   // [loss, perplexity]
    float* out_idx_f   = out_scalars + 2;                    // 16384 idx as float

    prep_w_kernel<<<dim3(N_CODES / 4), dim3(256), 0, stream>>>(weight, wpk, counts, lossac);
    gemm_kernel<<<dim3(M_TOTAL / M_BLOCK * NSPLIT), dim3(256), 0, stream>>>(z, wpk, candbuf);
    finish_kernel<<<dim3(M_TOTAL / 32), dim3(256), 0, stream>>>(
        z, weight, candbuf, counts, lossac, out, out_idx_f);
    finalize_kernel<<<dim3(1), dim3(256), 0, stream>>>(counts, lossac, out_scalars);
}

// Round 2
// 183.760 us; speedup vs baseline: 1.1566x; 1.0446x over previous
//
#include <hip/hip_runtime.h>
#include <stdint.h>

// VQ-VAE forward on MI355X — round 6.
// d_out (fp32): out[4194304] | loss[1] | perplexity[1] | idx_as_float[16384]
//
// prep     : fused. blocks [0,2048): weight -> fp16 fragment-major chunks (16 codes,
//            8 ks-blocks of 1024B + 64B hw bias at +8192, stride 9216B), hw =
//            1024 - |w|^2/2 folded into MFMA C-init; zero counts/loss.
//            blocks [2048,4096): z -> fp16 fragment-major z_pk[g][ks][q][r][8]
//            (g = row/16): gemm A-prologue becomes 32 coalesced 16B loads, no cvt.
// gemm     : 512 blocks x 4 waves (M_BLOCK=256 rows), TRIPLE-buffered shared LDS,
//            ONE barrier per chunk (stage distance 2 over 3 buffers makes the
//            overwrite target provably retired), counted vmcnt(3) (never 0 in loop),
//            s_setprio around MFMA cluster. 8 splits XCD-pinned; packed-key top-2.
// finish   : prune candidates by approx score (margin 0.5), fp64 rescore survivors
//            (float4-vectorized weight loads) -> exact idx, counts, loss; gather
//            weight[idx] -> out (LDS transposed).
// finalize : perplexity + loss scale.

#define M_TOTAL 16384
#define N_CODES 8192
#define KDIM    256
#define SPATIAL 4096
#define NSPLIT  8
#define CODES_PER_SPLIT  1024
#define CHUNK_CODES      16
#define CHUNKS_PER_SPLIT 64
#define CHUNK_BYTES      9216       // 8192 data + 64 hw + 960 pad
#define CHUNK_HALFS      4608
#define M_BLOCK          256

typedef _Float16 v8hf __attribute__((ext_vector_type(8)));
typedef _Float16 v4hf __attribute__((ext_vector_type(4)));
typedef float    v4f  __attribute__((ext_vector_type(4)));

// s_waitcnt imm (gfx9 encoding): [3:0] vmcnt lo, [6:4] expcnt, [11:8] lgkmcnt, [15:14] vmcnt hi
#define WAITCNT_VM3   0x0F73   // vmcnt(3),  lgkm/exp no-wait
#define WAITCNT_VM0   0x0F70   // vmcnt(0),  lgkm/exp no-wait

// ---------------------------------------------------------------- prep (+init)
// 4096 blocks x 256 thr.
// blocks [0,2048): one wave per code row. Fragment-major: code n -> chunk n>>4,
//   row n&15; element k at chunk byte (k>>5)*1024 + ((k>>3)&3)*256 + row*16 + (k&7)*2.
//   prep lane covers k = lane*4..+4. hw bias floats at chunk byte 8192 + row*4.
// blocks [2048,4096): one wave per (g, ks); lane (q,r) packs 8 halves
//   z_pk[g*4096 + ks*512 + q*128 + r*8 + j] = (f16) z[row=g*16+r][k=ks*32+q*8+j].
__global__ __launch_bounds__(256) void prep_kernel(
    const float* __restrict__ w, const float* __restrict__ z,
    _Float16* __restrict__ wpk, _Float16* __restrict__ z_pk,
    int* __restrict__ counts, double* __restrict__ loss_acc)
{
    const int t = threadIdx.x;
    const int lane = t & 63;
    if (blockIdx.x < 2048) {
        const int n = blockIdx.x * 4 + (t >> 6);
        v4f v = ((const v4f*)(w + (size_t)n * KDIM))[lane];
        v4hf hv;
        float s = 0.0f;
#pragma unroll
        for (int j = 0; j < 4; j++) {
            float f = v[j];
            s += f * f;
            hv[j] = (_Float16)f;
        }
        const int chunk = n >> 4;
        const int row   = n & 15;
        const int ks = lane >> 3;            // granule>>2
        const int qq = (lane >> 1) & 3;      // granule&3
        const int hh = lane & 1;
        size_t off = (size_t)chunk * CHUNK_HALFS + ks * 512 + qq * 128 + row * 8 + hh * 4;
        *(v4hf*)(wpk + off) = hv;
#pragma unroll
        for (int o = 32; o >= 1; o >>= 1) s += __shfl_xor(s, o);
        if (lane == 0) {
            float* hwp = (float*)((char*)wpk + (size_t)chunk * CHUNK_BYTES + 8192);
            hwp[row] = 1024.0f - 0.5f * s;   // C-init bias: acc = hw + dot > 0
        }
        const int gi = blockIdx.x * 256 + t;
        if (gi < N_CODES) counts[gi] = 0;
        if (gi == 0) *loss_acc = 0.0;
    } else {
        const int zi = blockIdx.x - 2048;
        const int gw = zi * 4 + (t >> 6);    // 0..8191
        const int g  = gw >> 3;              // 0..1023 (row group of 16)
        const int ks = gw & 7;
        const int q  = lane >> 4, r = lane & 15;
        const int row0 = g << 4;
        const size_t src = ((size_t)(row0 >> 12) << 20) + (size_t)((row0 & 4095) + r);
        const int k0 = ks * 32 + q * 8;
        v8hf hv;
#pragma unroll
        for (int j = 0; j < 8; j++)
            hv[j] = (_Float16)z[src + ((size_t)(k0 + j) << 12)];
        *(v8hf*)(z_pk + (size_t)g * 4096 + ks * 512 + q * 128 + r * 8) = hv;
    }
}

// ---------------------------------------------------------------- top-2 MAX merge (key desc, n asc on tie)
__device__ __forceinline__ void top2max_merge(uint32_t& v1, int& i1, uint32_t& v2, int& i2,
                                              uint32_t o1, int oi1, uint32_t o2, int oi2) {
    bool ob = (o1 > v1) || (o1 == v1 && oi1 < i1);
    uint32_t n1v, n2v; int n1i, n2i;
    if (ob) {
        bool t2 = (v1 > o2) || (v1 == o2 && i1 < oi2);
        n1v = o1; n1i = oi1;
        n2v = t2 ? v1 : o2; n2i = t2 ? i1 : oi2;
    } else {
        bool t2 = (o1 > v2) || (o1 == v2 && oi1 < i2);
        n1v = v1; n1i = i1;
        n2v = t2 ? o1 : v2; n2i = t2 ? oi1 : i2;
    }
    v1 = n1v; i1 = n1i; v2 = n2v; i2 = n2i;
}

// ---------------------------------------------------------------- gemm
// grid 512 = 64 row-blocks x 8 splits (split = bid&7 -> XCD-pinned); block = 4 waves.
// Triple-buffered shared LDS, counted vmcnt(3), ONE barrier per chunk.
__global__ __launch_bounds__(256, 2) void gemm_kernel(
    const _Float16* __restrict__ z_pk,
    const _Float16* __restrict__ wpk,
    int4* __restrict__ candbuf)          // [M_TOTAL][8] = {k1,n1,k2,n2}
{
    __shared__ __align__(16) _Float16 lds[3][CHUNK_HALFS];   // 3 x 9216 B

    const int bid   = blockIdx.x;
    const int split = bid & 7;
    const int rb    = bid >> 3;            // 0..63
    const int i0    = rb * M_BLOCK;
    const int tid   = threadIdx.x;
    const int wid   = tid >> 6;
    const int lane  = tid & 63;
    const int r     = lane & 15;
    const int q     = lane >> 4;

    const char* wsplit = (const char*)wpk + (size_t)split * CHUNKS_PER_SPLIT * CHUNK_BYTES;

    // cooperative stage: wave wid loads ks-blocks {2*wid, 2*wid+1} (16B/lane) + its
    // 256B slice of the hw/pad row (4B/lane) => exactly 3 vmem per wave per chunk.
    auto stage = [&](int c, _Float16* lbh) {
        const char* gb = wsplit + (size_t)c * CHUNK_BYTES;
        char* lb = (char*)lbh;
#pragma unroll
        for (int j = 0; j < 2; j++) {
            const int o = (wid * 2 + j) * 1024 + lane * 16;
            __builtin_amdgcn_global_load_lds(
                (const __attribute__((address_space(1))) void*)(gb + o),
                (__attribute__((address_space(3))) void*)(lb + o), 16, 0, 0);
        }
        const int oh = 8192 + wid * 256 + lane * 4;
        __builtin_amdgcn_global_load_lds(
            (const __attribute__((address_space(1))) void*)(gb + oh),
            (__attribute__((address_space(3))) void*)(lb + oh), 4, 0, 0);
    };

    stage(0, lds[0]);
    stage(1, lds[1]);

    // ---- A fragments: 32 coalesced 16B loads from fragment-major z_pk
    v8hf a[4][8];
    {
        const int g0 = (i0 + wid * 64) >> 4;   // rb*16 + wid*4
#pragma unroll
        for (int mt = 0; mt < 4; mt++)
#pragma unroll
        for (int ks = 0; ks < 8; ks++)
            a[mt][ks] = *(const v8hf*)(z_pk + (size_t)(g0 + mt) * 4096 + ks * 512 + q * 128 + r * 8);
    }

    uint32_t k1[4][4], k2[4][4];
#pragma unroll
    for (int mt = 0; mt < 4; mt++)
#pragma unroll
    for (int g = 0; g < 4; g++) { k1[mt][g] = 0u; k2[mt][g] = 0u; }

    auto compute = [&](int it, const _Float16* lbh) {
        const char* lb = (const char*)lbh;
        const float hwv = *(const float*)(lb + 8192 + r * 4);
        v4f acc[4];
#pragma unroll
        for (int mt = 0; mt < 4; mt++) acc[mt] = (v4f){hwv, hwv, hwv, hwv};

        __builtin_amdgcn_s_setprio(1);
#pragma unroll
        for (int ks = 0; ks < 8; ks++) {
            v8hf bh = *(const v8hf*)(lb + ks * 1024 + lane * 16);   // contiguous: no conflicts
#pragma unroll
            for (int mt = 0; mt < 4; mt++)
                acc[mt] = __builtin_amdgcn_mfma_f32_16x16x32_f16(a[mt][ks], bh, acc[mt], 0, 0, 0);
        }
        __builtin_amdgcn_s_setprio(0);

        // top-2 MAX of packed key: acc bits (distance = 2048 - 2*acc) | 6-bit chunk tag
        const uint32_t tag = (uint32_t)it;
#pragma unroll
        for (int mt = 0; mt < 4; mt++)
#pragma unroll
        for (int g = 0; g < 4; g++) {
            uint32_t key = (__float_as_uint(acc[mt][g]) & 0xFFFFFFC0u) | tag;
            uint32_t o1 = k1[mt][g], o2 = k2[mt][g];
            uint32_t mn = key < o1 ? key : o1;
            k2[mt][g] = o2 > mn ? o2 : mn;
            k1[mt][g] = key > o1 ? key : o1;
        }
    };

    // Single-barrier triple-buffer schedule. At iter-it top, outstanding vmem =
    // trio(it)+trio(it+1) (+A-loads at it=0 only); vmcnt(3) retires trio(it); the
    // barrier makes it everyone's. stage(it+2) overwrites the buffer of chunk it-1,
    // which every wave finished reading before arriving at this barrier.
    const _Float16 *pA = lds[0], *pB = lds[1];
    _Float16 *pC = lds[2];
#pragma unroll 1
    for (int it = 0; it < CHUNKS_PER_SPLIT - 2; it++) {
        __builtin_amdgcn_s_waitcnt(WAITCNT_VM3);
        __builtin_amdgcn_s_barrier();
        __builtin_amdgcn_sched_barrier(0);
        compute(it, pA);
        stage(it + 2, pC);
        const _Float16* tmp = pA; pA = pB; pB = pC; pC = (_Float16*)tmp;
    }
    __builtin_amdgcn_s_waitcnt(WAITCNT_VM3);
    __builtin_amdgcn_s_barrier();
    __builtin_amdgcn_sched_barrier(0);
    compute(CHUNKS_PER_SPLIT - 2, pA);
    __builtin_amdgcn_s_waitcnt(WAITCNT_VM0);
    __builtin_amdgcn_s_barrier();
    __builtin_amdgcn_sched_barrier(0);
    compute(CHUNKS_PER_SPLIT - 1, pB);

    // decode n, cross-lane top-2 over the 16 r-lanes, write per-split candidates
    const int nsbase = split * CODES_PER_SPLIT + r;
#pragma unroll
    for (int mt = 0; mt < 4; mt++) {
#pragma unroll
        for (int g = 0; g < 4; g++) {
            uint32_t K1 = k1[mt][g], K2 = k2[mt][g];
            int n1 = nsbase + (int)((K1 & 63u) << 4);
            int n2 = nsbase + (int)((K2 & 63u) << 4);
#pragma unroll
            for (int off = 1; off < 16; off <<= 1) {
                uint32_t o1 = __shfl_xor(K1, off);
                int     on1 = __shfl_xor(n1, off);
                uint32_t o2 = __shfl_xor(K2, off);
                int     on2 = __shfl_xor(n2, off);
                top2max_merge(K1, n1, K2, n2, o1, on1, o2, on2);
            }
            if (r == 0) {
                const int row = i0 + wid * 64 + mt * 16 + q * 4 + g;
                candbuf[(size_t)row * 8 + split] = make_int4((int)K1, n1, (int)K2, n2);
            }
        }
    }
}

// ---------------------------------------------------------------- finish
// 512 blocks x 256 thr, 32 rows: prune by approx score, fp64 rescore survivors,
// exact idx + counts + loss; gather weight[idx] -> out.
__global__ __launch_bounds__(256) void finish_kernel(
    const float* __restrict__ z, const float* __restrict__ weight,
    const int4* __restrict__ candbuf,
    int* __restrict__ counts, double* __restrict__ loss_acc,
    float* __restrict__ out, float* __restrict__ out_idx_f)
{
    __shared__ int4  s_cand[32][8];
    __shared__ float s_zw[32][KDIM + 1];
    __shared__ int   s_fi[32];
    __shared__ double s_loss[4];

    const int i0 = blockIdx.x * 32;
    const int b  = i0 >> 12;
    const int s0 = i0 & (SPATIAL - 1);
    const int t  = threadIdx.x;

    s_cand[t >> 3][t & 7] = candbuf[(size_t)(i0 + (t >> 3)) * 8 + (t & 7)];

    // z tile transpose: coalesced global -> LDS
    for (int e = t; e < 32 * KDIM; e += 256) {
        const int c = e >> 5, rr = e & 31;
        s_zw[rr][c] = z[((size_t)b << 20) + ((size_t)c << 12) + s0 + rr];
    }
    __syncthreads();

    const int row = t >> 3, seg = t & 7;
    float zs[32];
#pragma unroll
    for (int j = 0; j < 32; j++) zs[j] = s_zw[row][seg * 32 + j];

    // approx distances + min
    float da[16];
    float dmin_a = 3.4e38f;
#pragma unroll
    for (int sp = 0; sp < 8; sp++) {
        int4 c = s_cand[row][sp];
        da[sp * 2]     = 2048.0f - 2.0f * __uint_as_float((uint32_t)c.x & 0xFFFFFFC0u);
        da[sp * 2 + 1] = 2048.0f - 2.0f * __uint_as_float((uint32_t)c.z & 0xFFFFFFC0u);
        dmin_a = fminf(dmin_a, fminf(da[sp * 2], da[sp * 2 + 1]));
    }
    const float cutoff = dmin_a + 0.5f;

    double dbest = 1e300; int nbest = 0x7fffffff;
#pragma unroll 1
    for (int c = 0; c < 16; c++) {
        if (da[c] > cutoff) continue;
        int4 cc = s_cand[row][c >> 1];
        const int n = (c & 1) ? cc.w : cc.y;
        const v4f* wr = (const v4f*)(weight + (size_t)n * KDIM + seg * 32);
        double d = 0.0;
#pragma unroll
        for (int jj = 0; jj < 8; jj++) {
            v4f wv = wr[jj];
#pragma unroll
            for (int u = 0; u < 4; u++) {
                double df = (double)zs[jj * 4 + u] - (double)wv[u];
                d += df * df;
            }
        }
#pragma unroll
        for (int o = 1; o < 8; o <<= 1) d += __shfl_xor(d, o);
        if (d < dbest || (d == dbest && n < nbest)) { dbest = d; nbest = n; }
    }

    double lsum = 0.0;
    if (seg == 0) {
        s_fi[row] = nbest;
        out_idx_f[i0 + row] = (float)nbest;
        atomicAdd(&counts[nbest], 1);
        lsum = dbest;
    }
#pragma unroll
    for (int o = 1; o < 64; o <<= 1) lsum += __shfl_xor(lsum, o);
    if ((t & 63) == 0) s_loss[t >> 6] = lsum;
    __syncthreads();
    if (t == 0) atomicAdd(loss_acc, s_loss[0] + s_loss[1] + s_loss[2] + s_loss[3]);

    // gather weight[fi] -> LDS (reuse s_zw) -> transposed coalesced write
    for (int e = t; e < 32 * KDIM; e += 256) {
        const int rr = e >> 8, c = e & 255;
        s_zw[rr][c] = weight[(size_t)s_fi[rr] * KDIM + c];
    }
    __syncthreads();
    const int m = t & 31, c0 = t >> 5;
    const size_t obase = ((size_t)b << 20) + (size_t)(s0 + m);
    for (int c = c0; c < KDIM; c += 8)
        out[obase + ((size_t)c << 12)] = s_zw[m][c];
}

// ---------------------------------------------------------------- finalize
__global__ void finalize_kernel(const int* __restrict__ counts,
                                const double* __restrict__ loss_acc,
                                float* __restrict__ out_scalars)
{
    const int t = threadIdx.x;
    double s = 0.0;
    for (int n = t; n < N_CODES; n += 256) {
        double p = (double)counts[n] / (double)M_TOTAL;
        s -= p * log(p + 1e-10);
    }
#pragma unroll
    for (int o = 32; o >= 1; o >>= 1) s += __shfl_xor(s, o);
    __shared__ double sds[4];
    if ((t & 63) == 0) sds[t >> 6] = s;
    __syncthreads();
    if (t == 0) {
        double tot = sds[0] + sds[1] + sds[2] + sds[3];
        out_scalars[0] = (float)(0.25 * (*loss_acc) / (double)(M_TOTAL * KDIM));
        out_scalars[1] = (float)exp(tot);
    }
}

// ---------------------------------------------------------------- launch
extern "C" void kernel_launch(void* const* d_in, const int* in_sizes, int n_in,
                              void* d_out, int out_size, void* d_ws, size_t ws_size,
                              hipStream_t stream) {
    const float* z      = (const float*)d_in[0];   // 4*256*16*16*16
    const float* weight = (const float*)d_in[1];   // 8192*256
    float* out = (float*)d_out;

    size_t off = 0;
    auto carve = [&](size_t bytes) {
        void* p = (char*)d_ws + off;
        off += (bytes + 255) & ~(size_t)255;
        return p;
    };
    _Float16* wpk     = (_Float16*)carve((size_t)(N_CODES / CHUNK_CODES) * CHUNK_BYTES); // 4.72 MB
    _Float16* z_pk    = (_Float16*)carve((size_t)M_TOTAL * KDIM * 2);                    // 8.39 MB
    int4*     candbuf = (int4*)    carve((size_t)M_TOTAL * 8 * 16);                      // 2 MB
    int*      counts  = (int*)     carve((size_t)N_CODES * 4);
    double*   lossac  = (double*)  carve(16);

    float* out_scalars = out + (size_t)4 * KDIM * SPATIAL;   // [loss, perplexity]
    float* out_idx_f   = out_scalars + 2;                    // 16384 idx as float

    prep_kernel<<<dim3(4096), dim3(256), 0, stream>>>(weight, z, wpk, z_pk, counts, lossac);
    gemm_kernel<<<dim3(M_TOTAL / M_BLOCK * NSPLIT), dim3(256), 0, stream>>>(z_pk, wpk, candbuf);
    finish_kernel<<<dim3(M_TOTAL / 32), dim3(256), 0, stream>>>(
        z, weight, candbuf, counts, lossac, out, out_idx_f);
    finalize_kernel<<<dim3(1), dim3(256), 0, stream>>>(counts, lossac, out_scalars);
}